// Round 7
// baseline (2001.942 us; speedup 1.0000x reference)
//
#include <hip/hip_runtime.h>

// ReLuGRUCell — Round 7: ABLATION, instrument fixed.
// Real pipeline = round-4 kernel (unchanged, passes). Ablation variants now run
// FULL-M (512 blocks) with 6x K-work (96 iters) so each exceeds the real
// GEMM1's 261us and lands in rocprof top-5:
//   gemm_abl<1> nostage : ds_read + MFMA + barriers, no global_load_lds
//   gemm_abl<2> nodsread: stage + MFMA + barriers, no ds_read
//   gemm_abl<3> nomfma  : stage + ds_read + barriers, no MFMA
//   gemm_abl<4> free    : ds_read + lgkm + MFMA only, no barriers/vmcnt
// Reference: 6x-scaled full structure = ~1570us.
//
// ws layout:
//   A  [16384][3072] bf16, Wc [3072][2048] bf16, Z [16384][1024] bf16

typedef __bf16 bf16x8 __attribute__((ext_vector_type(8)));
typedef float f32x4 __attribute__((ext_vector_type(4)));

#define LDA 3072
#define LDB 2048
#define HALF 8192
#define HALF_B 16384
#define ABL_ITERS 96   // 6x the real kernel's 16

// ---------------- pack kernels ----------------

__global__ __launch_bounds__(256) void pack_A(const float* __restrict__ inp,
                                              const float* __restrict__ hx,
                                              __bf16* __restrict__ A) {
  int t = blockIdx.x * 256 + threadIdx.x;
  int row = t >> 7;
  int col = (t & 127) << 3;
  const float4* pi = reinterpret_cast<const float4*>(inp + ((size_t)row << 10) + col);
  const float4* ph = reinterpret_cast<const float4*>(hx + ((size_t)row << 10) + col);
  float4 a0 = pi[0], a1 = pi[1];
  float4 b0 = ph[0], b1 = ph[1];
  bf16x8 oa, ob;
  oa[0] = (__bf16)a0.x; oa[1] = (__bf16)a0.y; oa[2] = (__bf16)a0.z; oa[3] = (__bf16)a0.w;
  oa[4] = (__bf16)a1.x; oa[5] = (__bf16)a1.y; oa[6] = (__bf16)a1.z; oa[7] = (__bf16)a1.w;
  ob[0] = (__bf16)b0.x; ob[1] = (__bf16)b0.y; ob[2] = (__bf16)b0.z; ob[3] = (__bf16)b0.w;
  ob[4] = (__bf16)b1.x; ob[5] = (__bf16)b1.y; ob[6] = (__bf16)b1.z; ob[7] = (__bf16)b1.w;
  *reinterpret_cast<bf16x8*>(A + (size_t)row * LDA + col) = oa;
  *reinterpret_cast<bf16x8*>(A + (size_t)row * LDA + 1024 + col) = ob;
}

__global__ __launch_bounds__(256) void pack_W(const float* __restrict__ wih,
                                              const float* __restrict__ whh,
                                              __bf16* __restrict__ Wc) {
  int t = blockIdx.x * 256 + threadIdx.x;
  int n = t >> 7;
  int col = (t & 127) << 3;
  const float4* pi = reinterpret_cast<const float4*>(wih + ((size_t)n << 10) + col);
  const float4* ph = reinterpret_cast<const float4*>(whh + ((size_t)n << 10) + col);
  float4 a0 = pi[0], a1 = pi[1];
  float4 b0 = ph[0], b1 = ph[1];
  bf16x8 oa, ob;
  oa[0] = (__bf16)a0.x; oa[1] = (__bf16)a0.y; oa[2] = (__bf16)a0.z; oa[3] = (__bf16)a0.w;
  oa[4] = (__bf16)a1.x; oa[5] = (__bf16)a1.y; oa[6] = (__bf16)a1.z; oa[7] = (__bf16)a1.w;
  ob[0] = (__bf16)b0.x; ob[1] = (__bf16)b0.y; ob[2] = (__bf16)b0.z; ob[3] = (__bf16)b0.w;
  ob[4] = (__bf16)b1.x; ob[5] = (__bf16)b1.y; ob[6] = (__bf16)b1.z; ob[7] = (__bf16)b1.w;
  *reinterpret_cast<bf16x8*>(Wc + (size_t)n * LDB + col) = oa;
  *reinterpret_cast<bf16x8*>(Wc + (size_t)n * LDB + 1024 + col) = ob;
}

// ---------------- helpers ----------------

__device__ __forceinline__ uint32_t lds_off(const void* p) {
  return (uint32_t)(uintptr_t)(const __attribute__((address_space(3))) void*)p;
}

__device__ __forceinline__ void stage_half(const __bf16* g0, size_t ldg, __bf16* lh, int tid) {
#pragma unroll
  for (int ld = 0; ld < 2; ++ld) {
    int idx = ld * 512 + tid;
    int r = idx >> 3;
    int c = idx & 7;
    int sc = c ^ (r & 7);
    const __bf16* g = g0 + (size_t)r * ldg + sc * 8;
    __builtin_amdgcn_global_load_lds((const __attribute__((address_space(1))) void*)g,
                                     (__attribute__((address_space(3))) void*)(lh + idx * 8),
                                     16, 0, 0);
  }
}

__device__ __forceinline__ void ldA_asm(uint32_t base, int p, int lane, bf16x8 (&af)[2][2]) {
#pragma unroll
  for (int m = 0; m < 2; ++m)
#pragma unroll
    for (int kk = 0; kk < 2; ++kk) {
      int rr = p * 32 + m * 16 + (lane & 15);
      int c = kk * 4 + (lane >> 4);
      uint32_t addr = base + (uint32_t)(rr * 128 + ((c ^ (rr & 7)) << 4));
      asm volatile("ds_read_b128 %0, %1" : "=v"(af[m][kk]) : "v"(addr));
    }
}

__device__ __forceinline__ void ldB_asm(uint32_t base, int wcl, int lane, bf16x8 (&bfr)[4][2]) {
#pragma unroll
  for (int n = 0; n < 4; ++n)
#pragma unroll
    for (int kk = 0; kk < 2; ++kk) {
      int rr = wcl + n * 16 + (lane & 15);
      int c = kk * 4 + (lane >> 4);
      uint32_t addr = base + (uint32_t)(rr * 128 + ((c ^ (rr & 7)) << 4));
      asm volatile("ds_read_b128 %0, %1" : "=v"(bfr[n][kk]) : "v"(addr));
    }
}

__device__ __forceinline__ void mfma16(const bf16x8 (&af)[2][2], const bf16x8 (&bfr)[4][2],
                                       f32x4 (&acc)[8][4], int p) {
  __builtin_amdgcn_s_setprio(1);
#pragma unroll
  for (int kk = 0; kk < 2; ++kk)
#pragma unroll
    for (int m = 0; m < 2; ++m)
#pragma unroll
      for (int n = 0; n < 4; ++n)
        acc[p * 2 + m][n] =
            __builtin_amdgcn_mfma_f32_16x16x32_bf16(af[m][kk], bfr[n][kk], acc[p * 2 + m][n], 0, 0, 0);
  __builtin_amdgcn_s_setprio(0);
}

#define WAIT_VM(N)                             \
  __builtin_amdgcn_sched_barrier(0);           \
  asm volatile("s_waitcnt vmcnt(" #N ")");     \
  __builtin_amdgcn_sched_barrier(0);

#define PHASE_SYNC_MFMA(AF, BF, P)             \
  __builtin_amdgcn_s_barrier();                \
  asm volatile("s_waitcnt lgkmcnt(0)");        \
  __builtin_amdgcn_sched_barrier(0);           \
  mfma16(AF, BF, acc, P);                      \
  __builtin_amdgcn_s_barrier();

// ---------------- real fused 8-phase GEMM (round-4, unchanged) ----------------

template <int MODE>
__global__ __launch_bounds__(512, 2) void gemm8(__bf16* A, const __bf16* __restrict__ Wc,
                                                const float* __restrict__ hx,
                                                const float* __restrict__ bias,
                                                __bf16* __restrict__ Zbuf,
                                                float* __restrict__ out) {
  extern __shared__ char smem[];
  __bf16* sA = (__bf16*)smem;
  __bf16* sB = (__bf16*)smem + 4 * HALF;

  const int tid = threadIdx.x;
  const int lane = tid & 63;
  const int wid = tid >> 6;
  const int wr = wid >> 2;
  const int wc = wid & 3;
  const int wcl = (wc & 1) * 64;

  const int row0 = blockIdx.x * 256;
  const int col0 = blockIdx.y * 256;

  const __bf16* Abase = A + (size_t)row0 * LDA;
  const __bf16* Bbase = Wc + (size_t)((MODE ? 2048 : 0) + col0) * LDB;

  f32x4 acc[8][4] = {};

  auto stageA = [&](int t, int h) {
    int tw = t & 31;
    int k = (MODE && tw >= 16) ? tw * 64 + 1024 : tw * 64;
    stage_half(Abase + (size_t)(h * 128) * LDA + k, LDA, sA + (((t & 1) << 1) + h) * HALF, tid);
  };
  auto stageB = [&](int t, int h) {
    int tw = t & 31;
    stage_half(Bbase + (size_t)(h * 128) * LDB + tw * 64, LDB, sB + (((t & 1) << 1) + h) * HALF, tid);
  };

  const uint32_t sA0 = lds_off(sA);
  const uint32_t sB0 = lds_off(sB);
  const uint32_t bAE = sA0 + wr * HALF_B;
  const uint32_t bAO = sA0 + (2 + wr) * HALF_B;
  const uint32_t bBE = sB0 + (wc >> 1) * HALF_B;
  const uint32_t bBO = sB0 + (2 + (wc >> 1)) * HALF_B;

  stageA(0, 0); stageA(0, 1); stageB(0, 0); stageB(0, 1);
  stageB(1, 0); stageB(1, 1);
  WAIT_VM(4)
  __builtin_amdgcn_s_barrier();

  for (int i = 0; i < 16; ++i) {
    const int O = 2 * i + 1, EN = 2 * i + 2, ON = 2 * i + 3;
    bf16x8 af[2][2], bfE[4][2], bfO[4][2];
    ldA_asm(bAE, 0, lane, af); ldB_asm(bBE, wcl, lane, bfE);
    stageA(O, 0);
    PHASE_SYNC_MFMA(af, bfE, 0)
    ldA_asm(bAE, 1, lane, af);
    stageA(O, 1);
    PHASE_SYNC_MFMA(af, bfE, 1)
    ldA_asm(bAE, 2, lane, af);
    stageB(EN, 0);
    PHASE_SYNC_MFMA(af, bfE, 2)
    ldA_asm(bAE, 3, lane, af);
    stageB(EN, 1);
    WAIT_VM(4)
    PHASE_SYNC_MFMA(af, bfE, 3)
    ldA_asm(bAO, 0, lane, af); ldB_asm(bBO, wcl, lane, bfO);
    stageA(EN, 0);
    PHASE_SYNC_MFMA(af, bfO, 0)
    ldA_asm(bAO, 1, lane, af);
    stageA(EN, 1);
    PHASE_SYNC_MFMA(af, bfO, 1)
    ldA_asm(bAO, 2, lane, af);
    stageB(ON, 0);
    PHASE_SYNC_MFMA(af, bfO, 2)
    ldA_asm(bAO, 3, lane, af);
    stageB(ON, 1);
    WAIT_VM(4)
    PHASE_SYNC_MFMA(af, bfO, 3)
  }
  __builtin_amdgcn_sched_barrier(0);
  asm volatile("s_waitcnt vmcnt(0)");
  __builtin_amdgcn_sched_barrier(0);

#pragma unroll
  for (int m = 0; m < 8; ++m) {
#pragma unroll
    for (int n = 0; n < 4; ++n) {
      int col = col0 + wc * 64 + n * 16 + (lane & 15);
      int rbase = row0 + wr * 128 + m * 16 + (lane >> 4) * 4;
      if (MODE == 0) {
        int gate = col >> 10;
        int h = col & 1023;
        float b = bias[gate * 1024 + h];
#pragma unroll
        for (int jj = 0; jj < 4; ++jj) {
          int rg = rbase + jj;
          float x = acc[m][n][jj] + b;
          float s = 1.f / (1.f + __expf(-x));
          if (gate == 0) {
            Zbuf[(size_t)rg * 1024 + h] = (__bf16)s;
          } else {
            float hv = hx[(size_t)rg * 1024 + h];
            A[(size_t)rg * LDA + 2048 + h] = (__bf16)(hv * s);
          }
        }
      } else {
        float b = bias[2048 + col];
#pragma unroll
        for (int jj = 0; jj < 4; ++jj) {
          int rg = rbase + jj;
          float np = fmaxf(acc[m][n][jj] + b, 0.f);
          float z = (float)Zbuf[(size_t)rg * 1024 + col];
          float hv = hx[(size_t)rg * 1024 + col];
          out[(size_t)rg * 1024 + col] = (1.f - z) * np + z * hv;
        }
      }
    }
  }
}

// ---------------- ablation variants (dead, MODE-0 shape, full-M, 6x K) ----------------
// V1 nostage, V2 nodsread, V3 nomfma, V4 free-run (no barriers/vmcnt).

template <int V>
__global__ __launch_bounds__(512, 2) void gemm_abl(const __bf16* __restrict__ A,
                                                   const __bf16* __restrict__ Wc,
                                                   float* __restrict__ dump) {
  extern __shared__ char smem[];
  __bf16* sA = (__bf16*)smem;
  __bf16* sB = (__bf16*)smem + 4 * HALF;

  const int tid = threadIdx.x;
  const int lane = tid & 63;
  const int wid = tid >> 6;
  const int wr = wid >> 2;
  const int wc = wid & 3;
  const int wcl = (wc & 1) * 64;

  const int row0 = blockIdx.x * 256;
  const int col0 = blockIdx.y * 256;

  const __bf16* Abase = A + (size_t)row0 * LDA;
  const __bf16* Bbase = Wc + (size_t)col0 * LDB;

  f32x4 acc[8][4] = {};

  auto stageA = [&](int t, int h) {
    if constexpr (V == 1 || V == 4) return;
    int tw = t & 31;
    stage_half(Abase + (size_t)(h * 128) * LDA + tw * 64, LDA, sA + (((t & 1) << 1) + h) * HALF, tid);
  };
  auto stageB = [&](int t, int h) {
    if constexpr (V == 1 || V == 4) return;
    int tw = t & 31;
    stage_half(Bbase + (size_t)(h * 128) * LDB + tw * 64, LDB, sB + (((t & 1) << 1) + h) * HALF, tid);
  };

  const uint32_t sA0 = lds_off(sA);
  const uint32_t sB0 = lds_off(sB);
  const uint32_t bAE = sA0 + wr * HALF_B;
  const uint32_t bAO = sA0 + (2 + wr) * HALF_B;
  const uint32_t bBE = sB0 + (wc >> 1) * HALF_B;
  const uint32_t bBO = sB0 + (2 + (wc >> 1)) * HALF_B;

  bf16x8 af[2][2], bfE[4][2], bfO[4][2];
#pragma unroll
  for (int m = 0; m < 2; ++m)
#pragma unroll
    for (int k = 0; k < 2; ++k) {
      af[m][k] = bf16x8{};
      asm volatile("" : "+v"(af[m][k]));
    }
#pragma unroll
  for (int n = 0; n < 4; ++n)
#pragma unroll
    for (int k = 0; k < 2; ++k) {
      bfE[n][k] = bf16x8{}; asm volatile("" : "+v"(bfE[n][k]));
      bfO[n][k] = bf16x8{}; asm volatile("" : "+v"(bfO[n][k]));
    }

#define ABL_LDA(BASE, P)  if constexpr (V != 2) ldA_asm(BASE, P, lane, af);
#define ABL_LDB(BASE, F)  if constexpr (V != 2) ldB_asm(BASE, wcl, lane, F);
#define ABL_SYNC_MFMA(F, P)                                        \
  if constexpr (V != 4) __builtin_amdgcn_s_barrier();              \
  asm volatile("s_waitcnt lgkmcnt(0)");                            \
  __builtin_amdgcn_sched_barrier(0);                               \
  if constexpr (V != 3) mfma16(af, F, acc, P);                     \
  else { asm volatile("" :: "v"(af[0][0]), "v"(af[1][1]), "v"(F[0][0]), "v"(F[3][1])); } \
  if constexpr (V != 4) __builtin_amdgcn_s_barrier();
#define ABL_WVM(N)                                                 \
  if constexpr (V != 1 && V != 4) { WAIT_VM(N) }

  stageA(0, 0); stageA(0, 1); stageB(0, 0); stageB(0, 1);
  stageB(1, 0); stageB(1, 1);
  ABL_WVM(4)
  if constexpr (V != 4) __builtin_amdgcn_s_barrier();

  for (int i = 0; i < ABL_ITERS; ++i) {
    const int O = 2 * i + 1, EN = 2 * i + 2, ON = 2 * i + 3;
    ABL_LDA(bAE, 0) ABL_LDB(bBE, bfE)
    stageA(O, 0);
    ABL_SYNC_MFMA(bfE, 0)
    ABL_LDA(bAE, 1)
    stageA(O, 1);
    ABL_SYNC_MFMA(bfE, 1)
    ABL_LDA(bAE, 2)
    stageB(EN, 0);
    ABL_SYNC_MFMA(bfE, 2)
    ABL_LDA(bAE, 3)
    stageB(EN, 1);
    ABL_WVM(4)
    ABL_SYNC_MFMA(bfE, 3)
    ABL_LDA(bAO, 0) ABL_LDB(bBO, bfO)
    stageA(EN, 0);
    ABL_SYNC_MFMA(bfO, 0)
    ABL_LDA(bAO, 1)
    stageA(EN, 1);
    ABL_SYNC_MFMA(bfO, 1)
    ABL_LDA(bAO, 2)
    stageB(ON, 0);
    ABL_SYNC_MFMA(bfO, 2)
    ABL_LDA(bAO, 3)
    stageB(ON, 1);
    ABL_WVM(4)
    ABL_SYNC_MFMA(bfO, 3)
  }
  __builtin_amdgcn_sched_barrier(0);
  asm volatile("s_waitcnt vmcnt(0)");
  __builtin_amdgcn_sched_barrier(0);

  float s = 0.f;
#pragma unroll
  for (int m = 0; m < 8; ++m)
#pragma unroll
    for (int n = 0; n < 4; ++n) s += acc[m][n][0] + acc[m][n][3];
  s += (float)af[0][0][0] + (float)bfE[0][0][0] + (float)bfO[3][1][7];
  dump[(size_t)(blockIdx.y * gridDim.x + blockIdx.x) * 512 + tid] = s;
}

// ---------------- launch ----------------

extern "C" void kernel_launch(void* const* d_in, const int* in_sizes, int n_in,
                              void* d_out, int out_size, void* d_ws, size_t ws_size,
                              hipStream_t stream) {
  const float* inp  = (const float*)d_in[0];
  const float* hx   = (const float*)d_in[1];
  const float* wih  = (const float*)d_in[2];
  const float* whh  = (const float*)d_in[3];
  const float* bias = (const float*)d_in[4];
  float* out = (float*)d_out;

  char* ws = (char*)d_ws;
  __bf16* A  = (__bf16*)ws;
  __bf16* Wc = (__bf16*)(ws + 100663296);
  __bf16* Z  = (__bf16*)(ws + 100663296 + 12582912);
  float* dump = (float*)ws;  // A-region is fully rewritten by pack_A/gemm8<0> next call

  (void)hipFuncSetAttribute((const void*)gemm8<0>, hipFuncAttributeMaxDynamicSharedMemorySize, 131072);
  (void)hipFuncSetAttribute((const void*)gemm8<1>, hipFuncAttributeMaxDynamicSharedMemorySize, 131072);
  (void)hipFuncSetAttribute((const void*)gemm_abl<1>, hipFuncAttributeMaxDynamicSharedMemorySize, 131072);
  (void)hipFuncSetAttribute((const void*)gemm_abl<2>, hipFuncAttributeMaxDynamicSharedMemorySize, 131072);
  (void)hipFuncSetAttribute((const void*)gemm_abl<3>, hipFuncAttributeMaxDynamicSharedMemorySize, 131072);
  (void)hipFuncSetAttribute((const void*)gemm_abl<4>, hipFuncAttributeMaxDynamicSharedMemorySize, 131072);

  pack_A<<<8192, 256, 0, stream>>>(inp, hx, A);
  pack_W<<<1536, 256, 0, stream>>>(wih, whh, Wc);

  dim3 g1(16384 / 256, 2048 / 256);
  gemm8<0><<<g1, 512, 131072, stream>>>(A, Wc, hx, bias, Z, out);

  dim3 g2(16384 / 256, 1024 / 256);
  gemm8<1><<<g2, 512, 131072, stream>>>(A, Wc, hx, bias, Z, out);

  // ---- dead ablation dispatches, FULL-M, 6x K-work ----
  dim3 ga(16384 / 256, 2048 / 256);
  gemm_abl<1><<<ga, 512, 131072, stream>>>(A, Wc, dump);
  gemm_abl<2><<<ga, 512, 131072, stream>>>(A, Wc, dump);
  gemm_abl<3><<<ga, 512, 131072, stream>>>(A, Wc, dump);
  gemm_abl<4><<<ga, 512, 131072, stream>>>(A, Wc, dump);
}

// Round 8
// 325.548 us; speedup vs baseline: 6.1494x; 6.1494x over previous
//
#include <hip/hip_runtime.h>

// ReLuGRUCell: B=16384, D_IN=1024, H=1024, fp32 in/out, bf16 MFMA internally.
// Round 8: round-4 8-phase kernel + XCD-pinned col-panel mapping.
// Ablation (r7) showed: phase structure alone = 58% of peak; real kernel is
// staging-DELIVERY-bound at 4.1 TB/s (L2-thrash, L3-served). Fix: pin each
// XCD to one B col-panel (by' = lin % gy; XCD = lin % 8 -> by' constant per
// XCD). B re-reads (512 MB) become L2 hits; A read once per XCD from L3.
//
// ws layout:
//   A  [16384][3072] bf16 : cols 0:1024=input, 1024:2048=hx, 2048:3072=hx*r
//   Wc [3072][2048]  bf16 : row g*1024+h = [Wih[g][h][:], Whh[g][h][:]]
//   Z  [16384][1024] bf16 : sigmoid gate z

typedef __bf16 bf16x8 __attribute__((ext_vector_type(8)));
typedef float f32x4 __attribute__((ext_vector_type(4)));

#define LDA 3072
#define LDB 2048
#define HALF 8192
#define HALF_B 16384

// ---------------- pack kernels ----------------

__global__ __launch_bounds__(256) void pack_A(const float* __restrict__ inp,
                                              const float* __restrict__ hx,
                                              __bf16* __restrict__ A) {
  int t = blockIdx.x * 256 + threadIdx.x;
  int row = t >> 7;
  int col = (t & 127) << 3;
  const float4* pi = reinterpret_cast<const float4*>(inp + ((size_t)row << 10) + col);
  const float4* ph = reinterpret_cast<const float4*>(hx + ((size_t)row << 10) + col);
  float4 a0 = pi[0], a1 = pi[1];
  float4 b0 = ph[0], b1 = ph[1];
  bf16x8 oa, ob;
  oa[0] = (__bf16)a0.x; oa[1] = (__bf16)a0.y; oa[2] = (__bf16)a0.z; oa[3] = (__bf16)a0.w;
  oa[4] = (__bf16)a1.x; oa[5] = (__bf16)a1.y; oa[6] = (__bf16)a1.z; oa[7] = (__bf16)a1.w;
  ob[0] = (__bf16)b0.x; ob[1] = (__bf16)b0.y; ob[2] = (__bf16)b0.z; ob[3] = (__bf16)b0.w;
  ob[4] = (__bf16)b1.x; ob[5] = (__bf16)b1.y; ob[6] = (__bf16)b1.z; ob[7] = (__bf16)b1.w;
  *reinterpret_cast<bf16x8*>(A + (size_t)row * LDA + col) = oa;
  *reinterpret_cast<bf16x8*>(A + (size_t)row * LDA + 1024 + col) = ob;
}

__global__ __launch_bounds__(256) void pack_W(const float* __restrict__ wih,
                                              const float* __restrict__ whh,
                                              __bf16* __restrict__ Wc) {
  int t = blockIdx.x * 256 + threadIdx.x;
  int n = t >> 7;
  int col = (t & 127) << 3;
  const float4* pi = reinterpret_cast<const float4*>(wih + ((size_t)n << 10) + col);
  const float4* ph = reinterpret_cast<const float4*>(whh + ((size_t)n << 10) + col);
  float4 a0 = pi[0], a1 = pi[1];
  float4 b0 = ph[0], b1 = ph[1];
  bf16x8 oa, ob;
  oa[0] = (__bf16)a0.x; oa[1] = (__bf16)a0.y; oa[2] = (__bf16)a0.z; oa[3] = (__bf16)a0.w;
  oa[4] = (__bf16)a1.x; oa[5] = (__bf16)a1.y; oa[6] = (__bf16)a1.z; oa[7] = (__bf16)a1.w;
  ob[0] = (__bf16)b0.x; ob[1] = (__bf16)b0.y; ob[2] = (__bf16)b0.z; ob[3] = (__bf16)b0.w;
  ob[4] = (__bf16)b1.x; ob[5] = (__bf16)b1.y; ob[6] = (__bf16)b1.z; ob[7] = (__bf16)b1.w;
  *reinterpret_cast<bf16x8*>(Wc + (size_t)n * LDB + col) = oa;
  *reinterpret_cast<bf16x8*>(Wc + (size_t)n * LDB + 1024 + col) = ob;
}

// ---------------- helpers ----------------

__device__ __forceinline__ uint32_t lds_off(const void* p) {
  return (uint32_t)(uintptr_t)(const __attribute__((address_space(3))) void*)p;
}

__device__ __forceinline__ void stage_half(const __bf16* g0, size_t ldg, __bf16* lh, int tid) {
#pragma unroll
  for (int ld = 0; ld < 2; ++ld) {
    int idx = ld * 512 + tid;
    int r = idx >> 3;
    int c = idx & 7;
    int sc = c ^ (r & 7);
    const __bf16* g = g0 + (size_t)r * ldg + sc * 8;
    __builtin_amdgcn_global_load_lds((const __attribute__((address_space(1))) void*)g,
                                     (__attribute__((address_space(3))) void*)(lh + idx * 8),
                                     16, 0, 0);
  }
}

__device__ __forceinline__ void ldA_asm(uint32_t base, int p, int lane, bf16x8 (&af)[2][2]) {
#pragma unroll
  for (int m = 0; m < 2; ++m)
#pragma unroll
    for (int kk = 0; kk < 2; ++kk) {
      int rr = p * 32 + m * 16 + (lane & 15);
      int c = kk * 4 + (lane >> 4);
      uint32_t addr = base + (uint32_t)(rr * 128 + ((c ^ (rr & 7)) << 4));
      asm volatile("ds_read_b128 %0, %1" : "=v"(af[m][kk]) : "v"(addr));
    }
}

__device__ __forceinline__ void ldB_asm(uint32_t base, int wcl, int lane, bf16x8 (&bfr)[4][2]) {
#pragma unroll
  for (int n = 0; n < 4; ++n)
#pragma unroll
    for (int kk = 0; kk < 2; ++kk) {
      int rr = wcl + n * 16 + (lane & 15);
      int c = kk * 4 + (lane >> 4);
      uint32_t addr = base + (uint32_t)(rr * 128 + ((c ^ (rr & 7)) << 4));
      asm volatile("ds_read_b128 %0, %1" : "=v"(bfr[n][kk]) : "v"(addr));
    }
}

__device__ __forceinline__ void mfma16(const bf16x8 (&af)[2][2], const bf16x8 (&bfr)[4][2],
                                       f32x4 (&acc)[8][4], int p) {
  __builtin_amdgcn_s_setprio(1);
#pragma unroll
  for (int kk = 0; kk < 2; ++kk)
#pragma unroll
    for (int m = 0; m < 2; ++m)
#pragma unroll
      for (int n = 0; n < 4; ++n)
        acc[p * 2 + m][n] =
            __builtin_amdgcn_mfma_f32_16x16x32_bf16(af[m][kk], bfr[n][kk], acc[p * 2 + m][n], 0, 0, 0);
  __builtin_amdgcn_s_setprio(0);
}

#define WAIT_VM(N)                             \
  __builtin_amdgcn_sched_barrier(0);           \
  asm volatile("s_waitcnt vmcnt(" #N ")");     \
  __builtin_amdgcn_sched_barrier(0);

#define PHASE_SYNC_MFMA(AF, BF, P)             \
  __builtin_amdgcn_s_barrier();                \
  asm volatile("s_waitcnt lgkmcnt(0)");        \
  __builtin_amdgcn_sched_barrier(0);           \
  mfma16(AF, BF, acc, P);                      \
  __builtin_amdgcn_s_barrier();

// ---------------- fused 8-phase GEMM ----------------
// MODE 0: C = A[:,0:2048] @ Wc[0:2048]^T   -> z (Zbuf), r -> hxr (A cols 2048+)
// MODE 1: C = [input|hxr] @ Wc[2048:3072]^T -> out

template <int MODE>
__global__ __launch_bounds__(512, 2) void gemm8(__bf16* A, const __bf16* __restrict__ Wc,
                                                const float* __restrict__ hx,
                                                const float* __restrict__ bias,
                                                __bf16* __restrict__ Zbuf,
                                                float* __restrict__ out) {
  extern __shared__ char smem[];
  __bf16* sA = (__bf16*)smem;
  __bf16* sB = (__bf16*)smem + 4 * HALF;

  const int tid = threadIdx.x;
  const int lane = tid & 63;
  const int wid = tid >> 6;
  const int wr = wid >> 2;
  const int wc = wid & 3;
  const int wcl = (wc & 1) * 64;

  // ---- XCD-pinned col-panel mapping ----
  // HW dispatch: linear wg id round-robins XCDs (xcd = lin % 8). Remap so each
  // XCD serves ONE by (B col-panel, 1 MB -> L2-resident) and sweeps bx.
  // gy=8 (MODE0): by' = lin%8 -> constant per XCD. gy=4 (MODE1): by' = lin%4,
  // two XCDs per panel. Bijective: (lin%gy, lin/gy) covers the grid once.
  const int gy = gridDim.y;
  const int lin = blockIdx.y * gridDim.x + blockIdx.x;
  const int by = lin % gy;
  const int bx = lin / gy;

  const int row0 = bx * 256;
  const int col0 = by * 256;

  const __bf16* Abase = A + (size_t)row0 * LDA;
  const __bf16* Bbase = Wc + (size_t)((MODE ? 2048 : 0) + col0) * LDB;

  f32x4 acc[8][4] = {};

  auto stageA = [&](int t, int h) {
    int tw = t & 31;
    int k = (MODE && tw >= 16) ? tw * 64 + 1024 : tw * 64;
    stage_half(Abase + (size_t)(h * 128) * LDA + k, LDA, sA + (((t & 1) << 1) + h) * HALF, tid);
  };
  auto stageB = [&](int t, int h) {
    int tw = t & 31;
    stage_half(Bbase + (size_t)(h * 128) * LDB + tw * 64, LDB, sB + (((t & 1) << 1) + h) * HALF, tid);
  };

  const uint32_t sA0 = lds_off(sA);
  const uint32_t sB0 = lds_off(sB);
  const uint32_t bAE = sA0 + wr * HALF_B;
  const uint32_t bAO = sA0 + (2 + wr) * HALF_B;
  const uint32_t bBE = sB0 + (wc >> 1) * HALF_B;
  const uint32_t bBO = sB0 + (2 + (wc >> 1)) * HALF_B;

  stageA(0, 0); stageA(0, 1); stageB(0, 0); stageB(0, 1);
  stageB(1, 0); stageB(1, 1);
  WAIT_VM(4)
  __builtin_amdgcn_s_barrier();

  for (int i = 0; i < 16; ++i) {
    const int O = 2 * i + 1, EN = 2 * i + 2, ON = 2 * i + 3;
    bf16x8 af[2][2], bfE[4][2], bfO[4][2];
    ldA_asm(bAE, 0, lane, af); ldB_asm(bBE, wcl, lane, bfE);
    stageA(O, 0);
    PHASE_SYNC_MFMA(af, bfE, 0)
    ldA_asm(bAE, 1, lane, af);
    stageA(O, 1);
    PHASE_SYNC_MFMA(af, bfE, 1)
    ldA_asm(bAE, 2, lane, af);
    stageB(EN, 0);
    PHASE_SYNC_MFMA(af, bfE, 2)
    ldA_asm(bAE, 3, lane, af);
    stageB(EN, 1);
    WAIT_VM(4)
    PHASE_SYNC_MFMA(af, bfE, 3)
    ldA_asm(bAO, 0, lane, af); ldB_asm(bBO, wcl, lane, bfO);
    stageA(EN, 0);
    PHASE_SYNC_MFMA(af, bfO, 0)
    ldA_asm(bAO, 1, lane, af);
    stageA(EN, 1);
    PHASE_SYNC_MFMA(af, bfO, 1)
    ldA_asm(bAO, 2, lane, af);
    stageB(ON, 0);
    PHASE_SYNC_MFMA(af, bfO, 2)
    ldA_asm(bAO, 3, lane, af);
    stageB(ON, 1);
    WAIT_VM(4)
    PHASE_SYNC_MFMA(af, bfO, 3)
  }
  __builtin_amdgcn_sched_barrier(0);
  asm volatile("s_waitcnt vmcnt(0)");
  __builtin_amdgcn_sched_barrier(0);

  // ---- epilogue: C/D layout col=lane&15, row=(lane>>4)*4+j ----
#pragma unroll
  for (int m = 0; m < 8; ++m) {
#pragma unroll
    for (int n = 0; n < 4; ++n) {
      int col = col0 + wc * 64 + n * 16 + (lane & 15);
      int rbase = row0 + wr * 128 + m * 16 + (lane >> 4) * 4;
      if (MODE == 0) {
        int gate = col >> 10;
        int h = col & 1023;
        float b = bias[gate * 1024 + h];
#pragma unroll
        for (int jj = 0; jj < 4; ++jj) {
          int rg = rbase + jj;
          float x = acc[m][n][jj] + b;
          float s = 1.f / (1.f + __expf(-x));
          if (gate == 0) {
            Zbuf[(size_t)rg * 1024 + h] = (__bf16)s;
          } else {
            float hv = hx[(size_t)rg * 1024 + h];
            A[(size_t)rg * LDA + 2048 + h] = (__bf16)(hv * s);
          }
        }
      } else {
        float b = bias[2048 + col];
#pragma unroll
        for (int jj = 0; jj < 4; ++jj) {
          int rg = rbase + jj;
          float np = fmaxf(acc[m][n][jj] + b, 0.f);
          float z = (float)Zbuf[(size_t)rg * 1024 + col];
          float hv = hx[(size_t)rg * 1024 + col];
          out[(size_t)rg * 1024 + col] = (1.f - z) * np + z * hv;
        }
      }
    }
  }
}

// ---------------- launch ----------------

extern "C" void kernel_launch(void* const* d_in, const int* in_sizes, int n_in,
                              void* d_out, int out_size, void* d_ws, size_t ws_size,
                              hipStream_t stream) {
  const float* inp  = (const float*)d_in[0];
  const float* hx   = (const float*)d_in[1];
  const float* wih  = (const float*)d_in[2];
  const float* whh  = (const float*)d_in[3];
  const float* bias = (const float*)d_in[4];
  float* out = (float*)d_out;

  char* ws = (char*)d_ws;
  __bf16* A  = (__bf16*)ws;
  __bf16* Wc = (__bf16*)(ws + 100663296);
  __bf16* Z  = (__bf16*)(ws + 100663296 + 12582912);

  (void)hipFuncSetAttribute((const void*)gemm8<0>, hipFuncAttributeMaxDynamicSharedMemorySize, 131072);
  (void)hipFuncSetAttribute((const void*)gemm8<1>, hipFuncAttributeMaxDynamicSharedMemorySize, 131072);

  pack_A<<<8192, 256, 0, stream>>>(inp, hx, A);
  pack_W<<<1536, 256, 0, stream>>>(wih, whh, Wc);

  dim3 g1(16384 / 256, 2048 / 256);
  gemm8<0><<<g1, 512, 131072, stream>>>(A, Wc, hx, bias, Z, out);

  dim3 g2(16384 / 256, 1024 / 256);
  gemm8<1><<<g2, 512, 131072, stream>>>(A, Wc, hx, bias, Z, out);
}

// Round 9
// 325.238 us; speedup vs baseline: 6.1553x; 1.0010x over previous
//
#include <hip/hip_runtime.h>

// ReLuGRUCell: B=16384, D_IN=1024, H=1024, fp32 in/out, bf16 MFMA internally.
// Round 9: SWIZZLE REMOVED — fully linear staging source, linear LDS dest,
// linear ds_read (m198's verified config). Everything else = round-3 schedule
// (8-phase, counted vmcnt(4), clobber-free waits, C++ ds_reads).
// r7/r8 established: structure floor = 891 cyc/phase; streaming adds +1557
// at a tier-insensitive ~6.6 B/cyc/CU — the one delta vs the verified m198
// template is the 16B-granule source XOR. This round tests exactly that.
//
// ws layout:
//   A  [16384][3072] bf16 : cols 0:1024=input, 1024:2048=hx, 2048:3072=hx*r
//   Wc [3072][2048]  bf16 : row g*1024+h = [Wih[g][h][:], Whh[g][h][:]]
//   Z  [16384][1024] bf16 : sigmoid gate z

typedef __bf16 bf16x8 __attribute__((ext_vector_type(8)));
typedef float f32x4 __attribute__((ext_vector_type(4)));

#define LDA 3072
#define LDB 2048
#define HALF 8192
#define HALF_B 16384

// ---------------- pack kernels ----------------

__global__ __launch_bounds__(256) void pack_A(const float* __restrict__ inp,
                                              const float* __restrict__ hx,
                                              __bf16* __restrict__ A) {
  int t = blockIdx.x * 256 + threadIdx.x;
  int row = t >> 7;
  int col = (t & 127) << 3;
  const float4* pi = reinterpret_cast<const float4*>(inp + ((size_t)row << 10) + col);
  const float4* ph = reinterpret_cast<const float4*>(hx + ((size_t)row << 10) + col);
  float4 a0 = pi[0], a1 = pi[1];
  float4 b0 = ph[0], b1 = ph[1];
  bf16x8 oa, ob;
  oa[0] = (__bf16)a0.x; oa[1] = (__bf16)a0.y; oa[2] = (__bf16)a0.z; oa[3] = (__bf16)a0.w;
  oa[4] = (__bf16)a1.x; oa[5] = (__bf16)a1.y; oa[6] = (__bf16)a1.z; oa[7] = (__bf16)a1.w;
  ob[0] = (__bf16)b0.x; ob[1] = (__bf16)b0.y; ob[2] = (__bf16)b0.z; ob[3] = (__bf16)b0.w;
  ob[4] = (__bf16)b1.x; ob[5] = (__bf16)b1.y; ob[6] = (__bf16)b1.z; ob[7] = (__bf16)b1.w;
  *reinterpret_cast<bf16x8*>(A + (size_t)row * LDA + col) = oa;
  *reinterpret_cast<bf16x8*>(A + (size_t)row * LDA + 1024 + col) = ob;
}

__global__ __launch_bounds__(256) void pack_W(const float* __restrict__ wih,
                                              const float* __restrict__ whh,
                                              __bf16* __restrict__ Wc) {
  int t = blockIdx.x * 256 + threadIdx.x;
  int n = t >> 7;
  int col = (t & 127) << 3;
  const float4* pi = reinterpret_cast<const float4*>(wih + ((size_t)n << 10) + col);
  const float4* ph = reinterpret_cast<const float4*>(whh + ((size_t)n << 10) + col);
  float4 a0 = pi[0], a1 = pi[1];
  float4 b0 = ph[0], b1 = ph[1];
  bf16x8 oa, ob;
  oa[0] = (__bf16)a0.x; oa[1] = (__bf16)a0.y; oa[2] = (__bf16)a0.z; oa[3] = (__bf16)a0.w;
  oa[4] = (__bf16)a1.x; oa[5] = (__bf16)a1.y; oa[6] = (__bf16)a1.z; oa[7] = (__bf16)a1.w;
  ob[0] = (__bf16)b0.x; ob[1] = (__bf16)b0.y; ob[2] = (__bf16)b0.z; ob[3] = (__bf16)b0.w;
  ob[4] = (__bf16)b1.x; ob[5] = (__bf16)b1.y; ob[6] = (__bf16)b1.z; ob[7] = (__bf16)b1.w;
  *reinterpret_cast<bf16x8*>(Wc + (size_t)n * LDB + col) = oa;
  *reinterpret_cast<bf16x8*>(Wc + (size_t)n * LDB + 1024 + col) = ob;
}

// ---------------- helpers (ALL LINEAR — no XOR anywhere) ----------------

__device__ __forceinline__ void stage_half(const __bf16* g0, size_t ldg, __bf16* lh, int tid) {
  // [128][64] bf16 half-tile; linear source, linear LDS dest.
#pragma unroll
  for (int ld = 0; ld < 2; ++ld) {
    int idx = ld * 512 + tid;  // 16B chunk index 0..1023
    int r = idx >> 3;
    int c = idx & 7;
    const __bf16* g = g0 + (size_t)r * ldg + c * 8;
    __builtin_amdgcn_global_load_lds((const __attribute__((address_space(1))) void*)g,
                                     (__attribute__((address_space(3))) void*)(lh + idx * 8),
                                     16, 0, 0);
  }
}

__device__ __forceinline__ void ldA(const __bf16* sAh, int p, int lane, bf16x8 (&af)[2][2]) {
#pragma unroll
  for (int m = 0; m < 2; ++m)
#pragma unroll
    for (int kk = 0; kk < 2; ++kk) {
      int rr = p * 32 + m * 16 + (lane & 15);
      int c = kk * 4 + (lane >> 4);
      af[m][kk] = *reinterpret_cast<const bf16x8*>(sAh + rr * 64 + c * 8);
    }
}

__device__ __forceinline__ void ldB(const __bf16* sBh, int wcl, int lane, bf16x8 (&bfr)[4][2]) {
#pragma unroll
  for (int n = 0; n < 4; ++n)
#pragma unroll
    for (int kk = 0; kk < 2; ++kk) {
      int rr = wcl + n * 16 + (lane & 15);
      int c = kk * 4 + (lane >> 4);
      bfr[n][kk] = *reinterpret_cast<const bf16x8*>(sBh + rr * 64 + c * 8);
    }
}

__device__ __forceinline__ void mfma16(const bf16x8 (&af)[2][2], const bf16x8 (&bfr)[4][2],
                                       f32x4 (&acc)[8][4], int p) {
  __builtin_amdgcn_s_setprio(1);
#pragma unroll
  for (int kk = 0; kk < 2; ++kk)
#pragma unroll
    for (int m = 0; m < 2; ++m)
#pragma unroll
      for (int n = 0; n < 4; ++n)
        acc[p * 2 + m][n] =
            __builtin_amdgcn_mfma_f32_16x16x32_bf16(af[m][kk], bfr[n][kk], acc[p * 2 + m][n], 0, 0, 0);
  __builtin_amdgcn_s_setprio(0);
}

#define WAIT_VM(N)                             \
  __builtin_amdgcn_sched_barrier(0);           \
  asm volatile("s_waitcnt vmcnt(" #N ")");     \
  __builtin_amdgcn_sched_barrier(0);

#define PHASE_SYNC_MFMA(AF, BF, P)             \
  __builtin_amdgcn_s_barrier();                \
  asm volatile("s_waitcnt lgkmcnt(0)");        \
  __builtin_amdgcn_sched_barrier(0);           \
  mfma16(AF, BF, acc, P);                      \
  __builtin_amdgcn_s_barrier();

// ---------------- fused 8-phase GEMM ----------------
// MODE 0: C = A[:,0:2048] @ Wc[0:2048]^T   -> z (Zbuf), r -> hxr (A cols 2048+)
// MODE 1: C = [input|hxr] @ Wc[2048:3072]^T -> out
// 256x256 tile, BK=64, 8 waves (2Mx4N). Stage order per iter i:
//   ph1: O.A0  ph2: O.A1  ph3: (E+2).B0  ph4: (E+2).B1 + vmcnt(4)
//   ph5: (E+2).A0  ph6: (E+2).A1  ph7: (O+2).B0  ph8: (O+2).B1 + vmcnt(4)

template <int MODE>
__global__ __launch_bounds__(512, 2) void gemm8(__bf16* A, const __bf16* __restrict__ Wc,
                                                const float* __restrict__ hx,
                                                const float* __restrict__ bias,
                                                __bf16* __restrict__ Zbuf,
                                                float* __restrict__ out) {
  extern __shared__ char smem[];
  __bf16* sA = (__bf16*)smem;             // [2 parity][2 half][HALF]
  __bf16* sB = (__bf16*)smem + 4 * HALF;  // [2 parity][2 half][HALF]

  const int tid = threadIdx.x;
  const int lane = tid & 63;
  const int wid = tid >> 6;
  const int wr = wid >> 2;
  const int wc = wid & 3;
  const int wcl = (wc & 1) * 64;

  const int row0 = blockIdx.x * 256;
  const int col0 = blockIdx.y * 256;

  const __bf16* Abase = A + (size_t)row0 * LDA;
  const __bf16* Bbase = Wc + (size_t)((MODE ? 2048 : 0) + col0) * LDB;

  f32x4 acc[8][4] = {};

  auto stageA = [&](int t, int h) {
    int tw = t & 31;
    int k = (MODE && tw >= 16) ? tw * 64 + 1024 : tw * 64;
    stage_half(Abase + (size_t)(h * 128) * LDA + k, LDA, sA + (((t & 1) << 1) + h) * HALF, tid);
  };
  auto stageB = [&](int t, int h) {
    int tw = t & 31;
    stage_half(Bbase + (size_t)(h * 128) * LDB + tw * 64, LDB, sB + (((t & 1) << 1) + h) * HALF, tid);
  };

  const __bf16* sAE = sA + wr * HALF;
  const __bf16* sAO = sA + (2 + wr) * HALF;
  const __bf16* sBE = sB + (wc >> 1) * HALF;
  const __bf16* sBO = sB + (2 + (wc >> 1)) * HALF;

  stageA(0, 0); stageA(0, 1); stageB(0, 0); stageB(0, 1);
  stageB(1, 0); stageB(1, 1);
  WAIT_VM(4)
  __builtin_amdgcn_s_barrier();

  for (int i = 0; i < 16; ++i) {
    const int O = 2 * i + 1, EN = 2 * i + 2, ON = 2 * i + 3;
    bf16x8 af[2][2], bfE[4][2], bfO[4][2];
    // ph1
    ldA(sAE, 0, lane, af); ldB(sBE, wcl, lane, bfE);
    stageA(O, 0);
    PHASE_SYNC_MFMA(af, bfE, 0)
    // ph2
    ldA(sAE, 1, lane, af);
    stageA(O, 1);
    PHASE_SYNC_MFMA(af, bfE, 1)
    // ph3
    ldA(sAE, 2, lane, af);
    stageB(EN, 0);
    PHASE_SYNC_MFMA(af, bfE, 2)
    // ph4
    ldA(sAE, 3, lane, af);
    stageB(EN, 1);
    WAIT_VM(4)
    PHASE_SYNC_MFMA(af, bfE, 3)
    // ph5
    ldA(sAO, 0, lane, af); ldB(sBO, wcl, lane, bfO);
    stageA(EN, 0);
    PHASE_SYNC_MFMA(af, bfO, 0)
    // ph6
    ldA(sAO, 1, lane, af);
    stageA(EN, 1);
    PHASE_SYNC_MFMA(af, bfO, 1)
    // ph7
    ldA(sAO, 2, lane, af);
    stageB(ON, 0);
    PHASE_SYNC_MFMA(af, bfO, 2)
    // ph8
    ldA(sAO, 3, lane, af);
    stageB(ON, 1);
    WAIT_VM(4)
    PHASE_SYNC_MFMA(af, bfO, 3)
  }
  __builtin_amdgcn_sched_barrier(0);
  asm volatile("s_waitcnt vmcnt(0)");
  __builtin_amdgcn_sched_barrier(0);

  // ---- epilogue: C/D layout col=lane&15, row=(lane>>4)*4+j ----
#pragma unroll
  for (int m = 0; m < 8; ++m) {
#pragma unroll
    for (int n = 0; n < 4; ++n) {
      int col = col0 + wc * 64 + n * 16 + (lane & 15);
      int rbase = row0 + wr * 128 + m * 16 + (lane >> 4) * 4;
      if (MODE == 0) {
        int gate = col >> 10;
        int h = col & 1023;
        float b = bias[gate * 1024 + h];
#pragma unroll
        for (int jj = 0; jj < 4; ++jj) {
          int rg = rbase + jj;
          float x = acc[m][n][jj] + b;
          float s = 1.f / (1.f + __expf(-x));
          if (gate == 0) {
            Zbuf[(size_t)rg * 1024 + h] = (__bf16)s;
          } else {
            float hv = hx[(size_t)rg * 1024 + h];
            A[(size_t)rg * LDA + 2048 + h] = (__bf16)(hv * s);
          }
        }
      } else {
        float b = bias[2048 + col];
#pragma unroll
        for (int jj = 0; jj < 4; ++jj) {
          int rg = rbase + jj;
          float np = fmaxf(acc[m][n][jj] + b, 0.f);
          float z = (float)Zbuf[(size_t)rg * 1024 + col];
          float hv = hx[(size_t)rg * 1024 + col];
          out[(size_t)rg * 1024 + col] = (1.f - z) * np + z * hv;
        }
      }
    }
  }
}

// ---------------- launch ----------------

extern "C" void kernel_launch(void* const* d_in, const int* in_sizes, int n_in,
                              void* d_out, int out_size, void* d_ws, size_t ws_size,
                              hipStream_t stream) {
  const float* inp  = (const float*)d_in[0];
  const float* hx   = (const float*)d_in[1];
  const float* wih  = (const float*)d_in[2];
  const float* whh  = (const float*)d_in[3];
  const float* bias = (const float*)d_in[4];
  float* out = (float*)d_out;

  char* ws = (char*)d_ws;
  __bf16* A  = (__bf16*)ws;
  __bf16* Wc = (__bf16*)(ws + 100663296);
  __bf16* Z  = (__bf16*)(ws + 100663296 + 12582912);

  (void)hipFuncSetAttribute((const void*)gemm8<0>, hipFuncAttributeMaxDynamicSharedMemorySize, 131072);
  (void)hipFuncSetAttribute((const void*)gemm8<1>, hipFuncAttributeMaxDynamicSharedMemorySize, 131072);

  pack_A<<<8192, 256, 0, stream>>>(inp, hx, A);
  pack_W<<<1536, 256, 0, stream>>>(wih, whh, Wc);

  dim3 g1(16384 / 256, 2048 / 256);
  gemm8<0><<<g1, 512, 131072, stream>>>(A, Wc, hx, bias, Z, out);

  dim3 g2(16384 / 256, 1024 / 256);
  gemm8<1><<<g2, 512, 131072, stream>>>(A, Wc, hx, bias, Z, out);
}

// Round 10
// 293.367 us; speedup vs baseline: 6.8240x; 1.1086x over previous
//
#include <hip/hip_runtime.h>

// ReLuGRUCell: B=16384, D_IN=1024, H=1024, fp32 in/out, bf16 MFMA internally.
// Round 10: r4 kernel with swizzle granule changed 16B/3-bit -> 32B/2-bit.
// Theory: 16B-granule XOR reverses lane pairs within 32B -> VMEM coalescer
// splits requests -> staging throttled to ~6.7 B/cyc/CU. 32B-granule keeps
// lane pairs ascending-contiguous (m201's st_16x32 property) while still
// spreading stride-128B ds_reads across all four 32B bank groups (~4-way).
//
// ws layout:
//   A  [16384][3072] bf16 : cols 0:1024=input, 1024:2048=hx, 2048:3072=hx*r
//   Wc [3072][2048]  bf16 : row g*1024+h = [Wih[g][h][:], Whh[g][h][:]]
//   Z  [16384][1024] bf16 : sigmoid gate z

typedef __bf16 bf16x8 __attribute__((ext_vector_type(8)));
typedef float f32x4 __attribute__((ext_vector_type(4)));

#define LDA 3072
#define LDB 2048
#define HALF 8192
#define HALF_B 16384

// ---------------- pack kernels ----------------

__global__ __launch_bounds__(256) void pack_A(const float* __restrict__ inp,
                                              const float* __restrict__ hx,
                                              __bf16* __restrict__ A) {
  int t = blockIdx.x * 256 + threadIdx.x;
  int row = t >> 7;
  int col = (t & 127) << 3;
  const float4* pi = reinterpret_cast<const float4*>(inp + ((size_t)row << 10) + col);
  const float4* ph = reinterpret_cast<const float4*>(hx + ((size_t)row << 10) + col);
  float4 a0 = pi[0], a1 = pi[1];
  float4 b0 = ph[0], b1 = ph[1];
  bf16x8 oa, ob;
  oa[0] = (__bf16)a0.x; oa[1] = (__bf16)a0.y; oa[2] = (__bf16)a0.z; oa[3] = (__bf16)a0.w;
  oa[4] = (__bf16)a1.x; oa[5] = (__bf16)a1.y; oa[6] = (__bf16)a1.z; oa[7] = (__bf16)a1.w;
  ob[0] = (__bf16)b0.x; ob[1] = (__bf16)b0.y; ob[2] = (__bf16)b0.z; ob[3] = (__bf16)b0.w;
  ob[4] = (__bf16)b1.x; ob[5] = (__bf16)b1.y; ob[6] = (__bf16)b1.z; ob[7] = (__bf16)b1.w;
  *reinterpret_cast<bf16x8*>(A + (size_t)row * LDA + col) = oa;
  *reinterpret_cast<bf16x8*>(A + (size_t)row * LDA + 1024 + col) = ob;
}

__global__ __launch_bounds__(256) void pack_W(const float* __restrict__ wih,
                                              const float* __restrict__ whh,
                                              __bf16* __restrict__ Wc) {
  int t = blockIdx.x * 256 + threadIdx.x;
  int n = t >> 7;
  int col = (t & 127) << 3;
  const float4* pi = reinterpret_cast<const float4*>(wih + ((size_t)n << 10) + col);
  const float4* ph = reinterpret_cast<const float4*>(whh + ((size_t)n << 10) + col);
  float4 a0 = pi[0], a1 = pi[1];
  float4 b0 = ph[0], b1 = ph[1];
  bf16x8 oa, ob;
  oa[0] = (__bf16)a0.x; oa[1] = (__bf16)a0.y; oa[2] = (__bf16)a0.z; oa[3] = (__bf16)a0.w;
  oa[4] = (__bf16)a1.x; oa[5] = (__bf16)a1.y; oa[6] = (__bf16)a1.z; oa[7] = (__bf16)a1.w;
  ob[0] = (__bf16)b0.x; ob[1] = (__bf16)b0.y; ob[2] = (__bf16)b0.z; ob[3] = (__bf16)b0.w;
  ob[4] = (__bf16)b1.x; ob[5] = (__bf16)b1.y; ob[6] = (__bf16)b1.z; ob[7] = (__bf16)b1.w;
  *reinterpret_cast<bf16x8*>(Wc + (size_t)n * LDB + col) = oa;
  *reinterpret_cast<bf16x8*>(Wc + (size_t)n * LDB + 1024 + col) = ob;
}

// ---------------- helpers ----------------

__device__ __forceinline__ uint32_t lds_off(const void* p) {
  return (uint32_t)(uintptr_t)(const __attribute__((address_space(3))) void*)p;
}

// 32B-granule 2-bit swizzle: 32B-unit u (chunk pair) XORed with (row & 3).
// On 16B-chunk index c (0..7): c' = c ^ ((r & 3) << 1). Lane pairs stay
// ascending-contiguous within 32B -> coalescer-safe; inverse == itself.
__device__ __forceinline__ void stage_half(const __bf16* g0, size_t ldg, __bf16* lh, int tid) {
#pragma unroll
  for (int ld = 0; ld < 2; ++ld) {
    int idx = ld * 512 + tid;  // 16B chunk index 0..1023
    int r = idx >> 3;
    int c = idx & 7;
    int sc = c ^ ((r & 3) << 1);
    const __bf16* g = g0 + (size_t)r * ldg + sc * 8;
    __builtin_amdgcn_global_load_lds((const __attribute__((address_space(1))) void*)g,
                                     (__attribute__((address_space(3))) void*)(lh + idx * 8),
                                     16, 0, 0);
  }
}

// Opaque ds_read_b128 (invisible to SIInsertWaitcnts); ordering restored
// manually via s_barrier + lgkmcnt(0) + sched_barrier(0) (rule #18).
__device__ __forceinline__ void ldA_asm(uint32_t base, int p, int lane, bf16x8 (&af)[2][2]) {
#pragma unroll
  for (int m = 0; m < 2; ++m)
#pragma unroll
    for (int kk = 0; kk < 2; ++kk) {
      int rr = p * 32 + m * 16 + (lane & 15);
      int c = kk * 4 + (lane >> 4);
      uint32_t addr = base + (uint32_t)(rr * 128 + ((c ^ ((rr & 3) << 1)) << 4));
      asm volatile("ds_read_b128 %0, %1" : "=v"(af[m][kk]) : "v"(addr));
    }
}

__device__ __forceinline__ void ldB_asm(uint32_t base, int wcl, int lane, bf16x8 (&bfr)[4][2]) {
#pragma unroll
  for (int n = 0; n < 4; ++n)
#pragma unroll
    for (int kk = 0; kk < 2; ++kk) {
      int rr = wcl + n * 16 + (lane & 15);
      int c = kk * 4 + (lane >> 4);
      uint32_t addr = base + (uint32_t)(rr * 128 + ((c ^ ((rr & 3) << 1)) << 4));
      asm volatile("ds_read_b128 %0, %1" : "=v"(bfr[n][kk]) : "v"(addr));
    }
}

__device__ __forceinline__ void mfma16(const bf16x8 (&af)[2][2], const bf16x8 (&bfr)[4][2],
                                       f32x4 (&acc)[8][4], int p) {
  __builtin_amdgcn_s_setprio(1);
#pragma unroll
  for (int kk = 0; kk < 2; ++kk)
#pragma unroll
    for (int m = 0; m < 2; ++m)
#pragma unroll
      for (int n = 0; n < 4; ++n)
        acc[p * 2 + m][n] =
            __builtin_amdgcn_mfma_f32_16x16x32_bf16(af[m][kk], bfr[n][kk], acc[p * 2 + m][n], 0, 0, 0);
  __builtin_amdgcn_s_setprio(0);
}

#define WAIT_VM(N)                             \
  __builtin_amdgcn_sched_barrier(0);           \
  asm volatile("s_waitcnt vmcnt(" #N ")");     \
  __builtin_amdgcn_sched_barrier(0);

#define PHASE_SYNC_MFMA(AF, BF, P)             \
  __builtin_amdgcn_s_barrier();                \
  asm volatile("s_waitcnt lgkmcnt(0)");        \
  __builtin_amdgcn_sched_barrier(0);           \
  mfma16(AF, BF, acc, P);                      \
  __builtin_amdgcn_s_barrier();

// ---------------- fused 8-phase GEMM ----------------
// MODE 0: C = A[:,0:2048] @ Wc[0:2048]^T   -> z (Zbuf), r -> hxr (A cols 2048+)
// MODE 1: C = [input|hxr] @ Wc[2048:3072]^T -> out
// 256x256 tile, BK=64, 8 waves (2Mx4N). Stage order per iter i:
//   ph1: O.A0  ph2: O.A1  ph3: (E+2).B0  ph4: (E+2).B1 + vmcnt(4)
//   ph5: (E+2).A0  ph6: (E+2).A1  ph7: (O+2).B0  ph8: (O+2).B1 + vmcnt(4)

template <int MODE>
__global__ __launch_bounds__(512, 2) void gemm8(__bf16* A, const __bf16* __restrict__ Wc,
                                                const float* __restrict__ hx,
                                                const float* __restrict__ bias,
                                                __bf16* __restrict__ Zbuf,
                                                float* __restrict__ out) {
  extern __shared__ char smem[];
  __bf16* sA = (__bf16*)smem;
  __bf16* sB = (__bf16*)smem + 4 * HALF;

  const int tid = threadIdx.x;
  const int lane = tid & 63;
  const int wid = tid >> 6;
  const int wr = wid >> 2;
  const int wc = wid & 3;
  const int wcl = (wc & 1) * 64;

  const int row0 = blockIdx.x * 256;
  const int col0 = blockIdx.y * 256;

  const __bf16* Abase = A + (size_t)row0 * LDA;
  const __bf16* Bbase = Wc + (size_t)((MODE ? 2048 : 0) + col0) * LDB;

  f32x4 acc[8][4] = {};

  auto stageA = [&](int t, int h) {
    int tw = t & 31;
    int k = (MODE && tw >= 16) ? tw * 64 + 1024 : tw * 64;
    stage_half(Abase + (size_t)(h * 128) * LDA + k, LDA, sA + (((t & 1) << 1) + h) * HALF, tid);
  };
  auto stageB = [&](int t, int h) {
    int tw = t & 31;
    stage_half(Bbase + (size_t)(h * 128) * LDB + tw * 64, LDB, sB + (((t & 1) << 1) + h) * HALF, tid);
  };

  const uint32_t sA0 = lds_off(sA);
  const uint32_t sB0 = lds_off(sB);
  const uint32_t bAE = sA0 + wr * HALF_B;
  const uint32_t bAO = sA0 + (2 + wr) * HALF_B;
  const uint32_t bBE = sB0 + (wc >> 1) * HALF_B;
  const uint32_t bBO = sB0 + (2 + (wc >> 1)) * HALF_B;

  stageA(0, 0); stageA(0, 1); stageB(0, 0); stageB(0, 1);
  stageB(1, 0); stageB(1, 1);
  WAIT_VM(4)
  __builtin_amdgcn_s_barrier();

  for (int i = 0; i < 16; ++i) {
    const int O = 2 * i + 1, EN = 2 * i + 2, ON = 2 * i + 3;
    bf16x8 af[2][2], bfE[4][2], bfO[4][2];
    // ph1
    ldA_asm(bAE, 0, lane, af); ldB_asm(bBE, wcl, lane, bfE);
    stageA(O, 0);
    PHASE_SYNC_MFMA(af, bfE, 0)
    // ph2
    ldA_asm(bAE, 1, lane, af);
    stageA(O, 1);
    PHASE_SYNC_MFMA(af, bfE, 1)
    // ph3
    ldA_asm(bAE, 2, lane, af);
    stageB(EN, 0);
    PHASE_SYNC_MFMA(af, bfE, 2)
    // ph4
    ldA_asm(bAE, 3, lane, af);
    stageB(EN, 1);
    WAIT_VM(4)
    PHASE_SYNC_MFMA(af, bfE, 3)
    // ph5
    ldA_asm(bAO, 0, lane, af); ldB_asm(bBO, wcl, lane, bfO);
    stageA(EN, 0);
    PHASE_SYNC_MFMA(af, bfO, 0)
    // ph6
    ldA_asm(bAO, 1, lane, af);
    stageA(EN, 1);
    PHASE_SYNC_MFMA(af, bfO, 1)
    // ph7
    ldA_asm(bAO, 2, lane, af);
    stageB(ON, 0);
    PHASE_SYNC_MFMA(af, bfO, 2)
    // ph8
    ldA_asm(bAO, 3, lane, af);
    stageB(ON, 1);
    WAIT_VM(4)
    PHASE_SYNC_MFMA(af, bfO, 3)
  }
  __builtin_amdgcn_sched_barrier(0);
  asm volatile("s_waitcnt vmcnt(0)");
  __builtin_amdgcn_sched_barrier(0);

  // ---- epilogue: C/D layout col=lane&15, row=(lane>>4)*4+j ----
#pragma unroll
  for (int m = 0; m < 8; ++m) {
#pragma unroll
    for (int n = 0; n < 4; ++n) {
      int col = col0 + wc * 64 + n * 16 + (lane & 15);
      int rbase = row0 + wr * 128 + m * 16 + (lane >> 4) * 4;
      if (MODE == 0) {
        int gate = col >> 10;
        int h = col & 1023;
        float b = bias[gate * 1024 + h];
#pragma unroll
        for (int jj = 0; jj < 4; ++jj) {
          int rg = rbase + jj;
          float x = acc[m][n][jj] + b;
          float s = 1.f / (1.f + __expf(-x));
          if (gate == 0) {
            Zbuf[(size_t)rg * 1024 + h] = (__bf16)s;
          } else {
            float hv = hx[(size_t)rg * 1024 + h];
            A[(size_t)rg * LDA + 2048 + h] = (__bf16)(hv * s);
          }
        }
      } else {
        float b = bias[2048 + col];
#pragma unroll
        for (int jj = 0; jj < 4; ++jj) {
          int rg = rbase + jj;
          float np = fmaxf(acc[m][n][jj] + b, 0.f);
          float z = (float)Zbuf[(size_t)rg * 1024 + col];
          float hv = hx[(size_t)rg * 1024 + col];
          out[(size_t)rg * 1024 + col] = (1.f - z) * np + z * hv;
        }
      }
    }
  }
}

// ---------------- launch ----------------

extern "C" void kernel_launch(void* const* d_in, const int* in_sizes, int n_in,
                              void* d_out, int out_size, void* d_ws, size_t ws_size,
                              hipStream_t stream) {
  const float* inp  = (const float*)d_in[0];
  const float* hx   = (const float*)d_in[1];
  const float* wih  = (const float*)d_in[2];
  const float* whh  = (const float*)d_in[3];
  const float* bias = (const float*)d_in[4];
  float* out = (float*)d_out;

  char* ws = (char*)d_ws;
  __bf16* A  = (__bf16*)ws;
  __bf16* Wc = (__bf16*)(ws + 100663296);
  __bf16* Z  = (__bf16*)(ws + 100663296 + 12582912);

  (void)hipFuncSetAttribute((const void*)gemm8<0>, hipFuncAttributeMaxDynamicSharedMemorySize, 131072);
  (void)hipFuncSetAttribute((const void*)gemm8<1>, hipFuncAttributeMaxDynamicSharedMemorySize, 131072);

  pack_A<<<8192, 256, 0, stream>>>(inp, hx, A);
  pack_W<<<1536, 256, 0, stream>>>(wih, whh, Wc);

  dim3 g1(16384 / 256, 2048 / 256);
  gemm8<0><<<g1, 512, 131072, stream>>>(A, Wc, hx, bias, Z, out);

  dim3 g2(16384 / 256, 1024 / 256);
  gemm8<1><<<g2, 512, 131072, stream>>>(A, Wc, hx, bias, Z, out);
}